// Round 1
// baseline (254.880 us; speedup 1.0000x reference)
//
#include <hip/hip_runtime.h>
#include <math.h>

#define DELTA_V 0.5f
#define DELTA_D 3.0f
#define P_REG   0.001f

// workspace layout (float offsets)
#define OFF_BIN_CNT   0    // [4][2]
#define OFF_BIN_SUM   8    // [4][2][2]
#define OFF_BIN_VAR   24   // [4][2]
#define OFF_INST_CNT  32   // [4][6]
#define OFF_INST_SUM  56   // [4][6][5]
#define OFF_INST_VAR  176  // [4][6]
#define OFF_BIN_MEAN  200  // [4][2][2]
#define OFF_INST_MEAN 216  // [4][6][5]
#define OFF_BIN_LDR   336  // [4]
#define OFF_INST_LDR  340  // [4]
#define WS_FLOATS     344

// ---------------- Pass 1: per-label counts and sums ----------------
template<int K, int D>
__global__ void pass1_kernel(const float* __restrict__ pred,   // [B][D][MN]
                             const int*  __restrict__ labels,  // [B][MN]
                             float* __restrict__ cnt,          // [B][K]
                             float* __restrict__ sums,         // [B][K][D]
                             int MN) {
    const int b = blockIdx.y;
    const float4* pred4 = (const float4*)(pred + (size_t)b * D * MN);
    const int4*   lab4  = (const int4*)(labels + (size_t)b * MN);
    const int n4 = MN >> 2;
    constexpr int NV = K * (D + 1);

    float acc[K][D + 1];   // [k][0..D-1] = sums, [k][D] = count
    #pragma unroll
    for (int k = 0; k < K; ++k)
        #pragma unroll
        for (int j = 0; j <= D; ++j) acc[k][j] = 0.f;

    __shared__ float lred[NV];
    if (threadIdx.x < NV) lred[threadIdx.x] = 0.f;
    __syncthreads();

    const int stride = gridDim.x * blockDim.x;
    for (int i = blockIdx.x * blockDim.x + threadIdx.x; i < n4; i += stride) {
        int4 lv = lab4[i];
        int labs[4] = {lv.x, lv.y, lv.z, lv.w};
        float4 xv[D];
        #pragma unroll
        for (int d = 0; d < D; ++d) xv[d] = pred4[(size_t)d * n4 + i];
        const float* xs = (const float*)&xv[0];   // xs[d*4 + c]
        #pragma unroll
        for (int c = 0; c < 4; ++c) {
            const int lab = labs[c];
            #pragma unroll
            for (int k = 0; k < K; ++k) {
                const float ind = (lab == k) ? 1.f : 0.f;
                acc[k][D] += ind;
                #pragma unroll
                for (int d = 0; d < D; ++d)
                    acc[k][d] = fmaf(ind, xs[d * 4 + c], acc[k][d]);
            }
        }
    }

    // wave(64) shuffle reduce, then LDS, then one global atomic per value
    #pragma unroll
    for (int k = 0; k < K; ++k) {
        #pragma unroll
        for (int j = 0; j <= D; ++j) {
            float v = acc[k][j];
            for (int off = 32; off > 0; off >>= 1) v += __shfl_down(v, off);
            if ((threadIdx.x & 63) == 0) atomicAdd(&lred[k * (D + 1) + j], v);
        }
    }
    __syncthreads();
    if (threadIdx.x < NV) {
        const int k = threadIdx.x / (D + 1);
        const int j = threadIdx.x % (D + 1);
        const float v = lred[threadIdx.x];
        if (j == D) atomicAdd(&cnt[b * K + k], v);
        else        atomicAdd(&sums[(b * K + k) * D + j], v);
    }
}

// ---------------- Mid: means + push(dist) + reg terms (tiny) ----------------
__global__ void mid_kernel(float* __restrict__ ws) {
    const int t = threadIdx.x;
    if (t >= 8) return;
    const int isInst = t >> 2;
    const int b = t & 3;
    const int K = isInst ? 6 : 2;
    const int D = isInst ? 5 : 2;
    const float* cnt   = ws + (isInst ? OFF_INST_CNT  : OFF_BIN_CNT)  + b * K;
    const float* sums  = ws + (isInst ? OFF_INST_SUM  : OFF_BIN_SUM)  + b * K * D;
    float*       means = ws + (isInst ? OFF_INST_MEAN : OFF_BIN_MEAN) + b * K * D;

    float mu[6][5];
    for (int k = 0; k < K; ++k) {
        const float c = cnt[k];
        for (int d = 0; d < D; ++d) {
            mu[k][d] = sums[k * D + d] / c;
            means[k * D + d] = mu[k][d];
        }
    }
    float l_dist = 0.f, l_reg = 0.f;
    for (int i = 0; i < K; ++i) {
        float n2 = 0.f;
        for (int d = 0; d < D; ++d) n2 += mu[i][d] * mu[i][d];
        l_reg += sqrtf(n2);
        for (int j = 0; j < K; ++j) {
            if (i == j) continue;
            float s = 0.f;
            for (int d = 0; d < D; ++d) { const float df = mu[i][d] - mu[j][d]; s += df * df; }
            const float dn = fmaxf(2.f * DELTA_D - sqrtf(s), 0.f);
            l_dist += dn * dn;
        }
    }
    l_dist /= (float)(K * (K - 1));
    l_reg  /= (float)K;
    float* ldr = ws + (isInst ? OFF_INST_LDR : OFF_BIN_LDR);
    ldr[b] = l_dist + P_REG * l_reg;
}

// ---------------- Pass 2: hinged variance term ----------------
template<int K, int D>
__global__ void pass2_kernel(const float* __restrict__ pred,
                             const int*  __restrict__ labels,
                             const float* __restrict__ means,  // [B][K][D]
                             float* __restrict__ var,          // [B][K]
                             int MN) {
    const int b = blockIdx.y;
    __shared__ float mu[K * D];
    __shared__ float lred[K];
    if (threadIdx.x < K * D) mu[threadIdx.x] = means[b * K * D + threadIdx.x];
    if (threadIdx.x < K) lred[threadIdx.x] = 0.f;
    __syncthreads();

    const float4* pred4 = (const float4*)(pred + (size_t)b * D * MN);
    const int4*   lab4  = (const int4*)(labels + (size_t)b * MN);
    const int n4 = MN >> 2;

    float acc[K];
    #pragma unroll
    for (int k = 0; k < K; ++k) acc[k] = 0.f;

    const int stride = gridDim.x * blockDim.x;
    for (int i = blockIdx.x * blockDim.x + threadIdx.x; i < n4; i += stride) {
        int4 lv = lab4[i];
        int labs[4] = {lv.x, lv.y, lv.z, lv.w};
        float4 xv[D];
        #pragma unroll
        for (int d = 0; d < D; ++d) xv[d] = pred4[(size_t)d * n4 + i];
        const float* xs = (const float*)&xv[0];
        #pragma unroll
        for (int c = 0; c < 4; ++c) {
            const int lab = labs[c];
            float s = 0.f;
            #pragma unroll
            for (int d = 0; d < D; ++d) {
                const float df = mu[lab * D + d] - xs[d * 4 + c];
                s = fmaf(df, df, s);
            }
            const float dist = sqrtf(s);
            const float h = fmaxf(dist - DELTA_V, 0.f);
            const float h2 = h * h;
            #pragma unroll
            for (int k = 0; k < K; ++k)
                acc[k] += (lab == k) ? h2 : 0.f;
        }
    }

    #pragma unroll
    for (int k = 0; k < K; ++k) {
        float v = acc[k];
        for (int off = 32; off > 0; off >>= 1) v += __shfl_down(v, off);
        if ((threadIdx.x & 63) == 0) atomicAdd(&lred[k], v);
    }
    __syncthreads();
    if (threadIdx.x < K) atomicAdd(&var[b * K + threadIdx.x], lred[threadIdx.x]);
}

// ---------------- Final: fold into 2 scalars ----------------
__global__ void final_kernel(const float* __restrict__ ws, float* __restrict__ out) {
    if (threadIdx.x != 0 || blockIdx.x != 0) return;
    float tot[2] = {0.f, 0.f};
    for (int isInst = 0; isInst < 2; ++isInst) {
        const int K = isInst ? 6 : 2;
        const float* cnt = ws + (isInst ? OFF_INST_CNT : OFF_BIN_CNT);
        const float* var = ws + (isInst ? OFF_INST_VAR : OFF_BIN_VAR);
        const float* ldr = ws + (isInst ? OFF_INST_LDR : OFF_BIN_LDR);
        for (int b = 0; b < 4; ++b) {
            float lv = 0.f;
            for (int k = 0; k < K; ++k) lv += var[b * K + k] / cnt[b * K + k];
            lv /= (float)K;
            tot[isInst] += lv + ldr[b];
        }
    }
    out[0] = tot[0] * 0.25f;
    out[1] = tot[1] * 0.25f;
}

extern "C" void kernel_launch(void* const* d_in, const int* in_sizes, int n_in,
                              void* d_out, int out_size, void* d_ws, size_t ws_size,
                              hipStream_t stream) {
    const float* bin_logits  = (const float*)d_in[0];
    const int*   bin_labels  = (const int*)d_in[1];
    const float* inst_logits = (const float*)d_in[2];
    const int*   inst_labels = (const int*)d_in[3];
    float* ws  = (float*)d_ws;
    float* out = (float*)d_out;

    const int B  = 4;
    const int MN = in_sizes[1] / B;   // 524288

    hipMemsetAsync(d_ws, 0, WS_FLOATS * sizeof(float), stream);

    dim3 grid(512, B), block(256);
    pass1_kernel<2, 2><<<grid, block, 0, stream>>>(bin_logits,  bin_labels,
                                                   ws + OFF_BIN_CNT,  ws + OFF_BIN_SUM,  MN);
    pass1_kernel<6, 5><<<grid, block, 0, stream>>>(inst_logits, inst_labels,
                                                   ws + OFF_INST_CNT, ws + OFF_INST_SUM, MN);
    mid_kernel<<<1, 64, 0, stream>>>(ws);
    pass2_kernel<2, 2><<<grid, block, 0, stream>>>(bin_logits,  bin_labels,
                                                   ws + OFF_BIN_MEAN,  ws + OFF_BIN_VAR,  MN);
    pass2_kernel<6, 5><<<grid, block, 0, stream>>>(inst_logits, inst_labels,
                                                   ws + OFF_INST_MEAN, ws + OFF_INST_VAR, MN);
    final_kernel<<<1, 64, 0, stream>>>(ws, out);
}

// Round 2
// 140.228 us; speedup vs baseline: 1.8176x; 1.8176x over previous
//
#include <hip/hip_runtime.h>
#include <math.h>

#define DELTA_V 0.5f
#define DELTA_D 3.0f
#define P_REG   0.001f

#define BPS   128   // blocks per slice
#define TPB   256
#define NVMAX 36

// workspace layout (float offsets). every word we read is written first; no memset needed.
#define P1_OFF   0                        // pass1 partials [8][BPS][36]
#define CNT_OFF  (8 * BPS * 36)           // [8][6]
#define MEAN_OFF (CNT_OFF + 48)           // [8][30]
#define LDR_OFF  (MEAN_OFF + 240)         // [8]
#define P2_OFF   (LDR_OFF + 8)            // pass2 partials [8][BPS][6]

// ---------------- Pass 1 body: per-label counts and sums, block-partial output ----------------
template<int K, int D>
__device__ void pass1_body(const float* __restrict__ pred,   // [D][MN] for this batch
                           const int*  __restrict__ labels,  // [MN]
                           float* __restrict__ partials,     // [NVMAX] this block's slot
                           int n4, float (*lredW)[NVMAX]) {
    constexpr int NV = K * (D + 1);
    const float4* pred4 = (const float4*)pred;
    const int4*   lab4  = (const int4*)labels;

    float acc[K][D + 1];
    #pragma unroll
    for (int k = 0; k < K; ++k)
        #pragma unroll
        for (int j = 0; j <= D; ++j) acc[k][j] = 0.f;

    const int idx0   = blockIdx.x * TPB + threadIdx.x;
    const int stride = BPS * TPB;
    for (int i = idx0; i < n4; i += stride) {
        int4 lv = lab4[i];
        int labs[4] = {lv.x, lv.y, lv.z, lv.w};
        float4 xv[D];
        #pragma unroll
        for (int d = 0; d < D; ++d) xv[d] = pred4[(size_t)d * n4 + i];
        const float* xs = (const float*)&xv[0];   // xs[d*4 + c]
        #pragma unroll
        for (int c = 0; c < 4; ++c) {
            const int lab = labs[c];
            #pragma unroll
            for (int k = 0; k < K; ++k) {
                const float ind = (lab == k) ? 1.f : 0.f;
                acc[k][D] += ind;
                #pragma unroll
                for (int d = 0; d < D; ++d)
                    acc[k][d] = fmaf(ind, xs[d * 4 + c], acc[k][d]);
            }
        }
    }

    const int wave = threadIdx.x >> 6, lane = threadIdx.x & 63;
    #pragma unroll
    for (int k = 0; k < K; ++k) {
        #pragma unroll
        for (int j = 0; j <= D; ++j) {
            float v = acc[k][j];
            for (int off = 32; off > 0; off >>= 1) v += __shfl_down(v, off);
            if (lane == 0) lredW[wave][k * (D + 1) + j] = v;
        }
    }
    __syncthreads();
    if (threadIdx.x < NV) {
        const int t = threadIdx.x;
        partials[t] = lredW[0][t] + lredW[1][t] + lredW[2][t] + lredW[3][t];
    }
}

__global__ __launch_bounds__(TPB)
void pass1_fused(const float* __restrict__ bl, const int* __restrict__ bL,
                 const float* __restrict__ il, const int* __restrict__ iL,
                 float* __restrict__ ws, int MN) {
    const int s = blockIdx.y, b = s & 3;
    __shared__ float lredW[4][NVMAX];
    float* partials = ws + P1_OFF + (size_t)(s * BPS + blockIdx.x) * NVMAX;
    if (s < 4) pass1_body<2, 2>(bl + (size_t)b * 2 * MN, bL + (size_t)b * MN, partials, MN >> 2, lredW);
    else       pass1_body<6, 5>(il + (size_t)b * 5 * MN, iL + (size_t)b * MN, partials, MN >> 2, lredW);
}

// ---------------- Mid: reduce partials -> cnt/means, push(dist)+reg terms ----------------
__global__ void mid_kernel(float* __restrict__ ws) {
    const int s = blockIdx.x;
    const int isInst = s >> 2;
    const int K = isInst ? 6 : 2, D = isInst ? 5 : 2;
    const int NV = K * (D + 1);
    const float* P = ws + P1_OFF + (size_t)s * BPS * NVMAX;
    const int t = threadIdx.x;
    __shared__ float tot[NVMAX];
    __shared__ float muS[30];
    __shared__ float cntS[6];
    if (t < NV) {
        float v = 0.f;
        for (int j = 0; j < BPS; ++j) v += P[j * NVMAX + t];
        tot[t] = v;
        const int k = t / (D + 1), jj = t % (D + 1);
        if (jj == D) { cntS[k] = v; ws[CNT_OFF + s * 6 + k] = v; }
    }
    __syncthreads();
    if (t < NV) {
        const int k = t / (D + 1), jj = t % (D + 1);
        if (jj < D) {
            const float m = tot[t] / cntS[k];
            muS[k * D + jj] = m;
            ws[MEAN_OFF + s * 30 + k * D + jj] = m;
        }
    }
    __syncthreads();
    if (t == 0) {
        float l_dist = 0.f, l_reg = 0.f;
        for (int i = 0; i < K; ++i) {
            float n2 = 0.f;
            for (int d = 0; d < D; ++d) n2 += muS[i * D + d] * muS[i * D + d];
            l_reg += sqrtf(n2);
            for (int j = 0; j < K; ++j) {
                if (i == j) continue;
                float sq = 0.f;
                for (int d = 0; d < D; ++d) { const float df = muS[i * D + d] - muS[j * D + d]; sq += df * df; }
                const float dn = fmaxf(2.f * DELTA_D - sqrtf(sq), 0.f);
                l_dist += dn * dn;
            }
        }
        l_dist /= (float)(K * (K - 1));
        l_reg  /= (float)K;
        ws[LDR_OFF + s] = l_dist + P_REG * l_reg;
    }
}

// ---------------- Pass 2 body: hinged variance, block-partial output ----------------
template<int K, int D>
__device__ void pass2_body(const float* __restrict__ pred,
                           const int*  __restrict__ labels,
                           const float* __restrict__ means,   // [K*D]
                           float* __restrict__ partials,      // [6] this block's slot
                           int n4, float* mu, float (*lredW)[6]) {
    if (threadIdx.x < K * D) mu[threadIdx.x] = means[threadIdx.x];
    __syncthreads();

    const float4* pred4 = (const float4*)pred;
    const int4*   lab4  = (const int4*)labels;

    float acc[K];
    #pragma unroll
    for (int k = 0; k < K; ++k) acc[k] = 0.f;

    const int idx0   = blockIdx.x * TPB + threadIdx.x;
    const int stride = BPS * TPB;
    for (int i = idx0; i < n4; i += stride) {
        int4 lv = lab4[i];
        int labs[4] = {lv.x, lv.y, lv.z, lv.w};
        float4 xv[D];
        #pragma unroll
        for (int d = 0; d < D; ++d) xv[d] = pred4[(size_t)d * n4 + i];
        const float* xs = (const float*)&xv[0];
        #pragma unroll
        for (int c = 0; c < 4; ++c) {
            const int lab = labs[c];
            float sq = 0.f;
            #pragma unroll
            for (int d = 0; d < D; ++d) {
                const float df = mu[lab * D + d] - xs[d * 4 + c];
                sq = fmaf(df, df, sq);
            }
            const float h = fmaxf(sqrtf(sq) - DELTA_V, 0.f);
            const float h2 = h * h;
            #pragma unroll
            for (int k = 0; k < K; ++k)
                acc[k] += (lab == k) ? h2 : 0.f;
        }
    }

    const int wave = threadIdx.x >> 6, lane = threadIdx.x & 63;
    #pragma unroll
    for (int k = 0; k < K; ++k) {
        float v = acc[k];
        for (int off = 32; off > 0; off >>= 1) v += __shfl_down(v, off);
        if (lane == 0) lredW[wave][k] = v;
    }
    __syncthreads();
    if (threadIdx.x < K) {
        const int t = threadIdx.x;
        partials[t] = lredW[0][t] + lredW[1][t] + lredW[2][t] + lredW[3][t];
    }
}

__global__ __launch_bounds__(TPB)
void pass2_fused(const float* __restrict__ bl, const int* __restrict__ bL,
                 const float* __restrict__ il, const int* __restrict__ iL,
                 float* __restrict__ ws, int MN) {
    const int s = blockIdx.y, b = s & 3;
    __shared__ float mu[30];
    __shared__ float lredW[4][6];
    const float* means = ws + MEAN_OFF + s * 30;
    float* partials = ws + P2_OFF + (size_t)(s * BPS + blockIdx.x) * 6;
    if (s < 4) pass2_body<2, 2>(bl + (size_t)b * 2 * MN, bL + (size_t)b * MN, means, partials, MN >> 2, mu, lredW);
    else       pass2_body<6, 5>(il + (size_t)b * 5 * MN, iL + (size_t)b * MN, means, partials, MN >> 2, mu, lredW);
}

// ---------------- Final: fold into 2 scalars ----------------
__global__ void final_kernel(const float* __restrict__ ws, float* __restrict__ out) {
    __shared__ float contrib[48];
    const int t = threadIdx.x;
    if (t < 48) {
        const int s = t / 6, k = t % 6;
        const int Ks = (s < 4) ? 2 : 6;
        float c = 0.f;
        if (k < Ks) {
            float v = 0.f;
            for (int j = 0; j < BPS; ++j) v += ws[P2_OFF + (size_t)(s * BPS + j) * 6 + k];
            c = v / ws[CNT_OFF + s * 6 + k];
        }
        contrib[t] = c;
    }
    __syncthreads();
    if (t == 0) {
        float totB = 0.f, totI = 0.f;
        for (int s = 0; s < 8; ++s) {
            const int Ks = (s < 4) ? 2 : 6;
            float lv = 0.f;
            for (int k = 0; k < Ks; ++k) lv += contrib[s * 6 + k];
            lv /= (float)Ks;
            const float loss = lv + ws[LDR_OFF + s];
            if (s < 4) totB += loss; else totI += loss;
        }
        out[0] = totB * 0.25f;
        out[1] = totI * 0.25f;
    }
}

extern "C" void kernel_launch(void* const* d_in, const int* in_sizes, int n_in,
                              void* d_out, int out_size, void* d_ws, size_t ws_size,
                              hipStream_t stream) {
    const float* bin_logits  = (const float*)d_in[0];
    const int*   bin_labels  = (const int*)d_in[1];
    const float* inst_logits = (const float*)d_in[2];
    const int*   inst_labels = (const int*)d_in[3];
    float* ws  = (float*)d_ws;
    float* out = (float*)d_out;

    const int B  = 4;
    const int MN = in_sizes[1] / B;   // 524288

    dim3 grid(BPS, 8), block(TPB);
    pass1_fused<<<grid, block, 0, stream>>>(bin_logits, bin_labels, inst_logits, inst_labels, ws, MN);
    mid_kernel<<<8, 64, 0, stream>>>(ws);
    pass2_fused<<<grid, block, 0, stream>>>(bin_logits, bin_labels, inst_logits, inst_labels, ws, MN);
    final_kernel<<<1, 64, 0, stream>>>(ws, out);
}